// Round 2
// baseline (14926.390 us; speedup 1.0000x reference)
//
#include <hip/hip_runtime.h>
#include <math.h>

#define BB_ 32
#define TT_ 128
#define EE_ 64
#define HH_ 128
#define VV_ 32000
#define NMM 200      // matmul workgroups
#define NCELL 32     // cell workgroups (one per batch)
#define NWG (NMM + NCELL)
#define VW 160       // vocab rows per matmul wg (200*160 = 32000)

// ---- dynamic LDS layout (bytes) for matmul wgs ----
#define LHB_STRIDE 136              // floats per batch row (128 + pad)
#define OFF_LHB 0                   // float[32*136] = 17408  h tile, [b][k]
#define OFF_RDF 17408               // float[3*128*41] = 62976  k-split reduce (stride 41 dwords: conflict-free)
// cell wgs overlay (same dynamic buffer, different CUs)
#define OFF_SG  0                   // float[512] gates
#define OFF_SH  2048                // float[128] h
#define OFF_TOK 2560                // int token broadcast
#define DYN_LDS 98304               // 96KB: forces 1 wg/CU (160KB pool)

// ---- workspace layout (bytes) ----
#define WS_GBEST 0                  // u64[129*32] = 33024  per-(step,batch) argmax (packed)
#define WS_HCNT  33024              // u32[160] = 640       cells done with step s
#define WS_MCNT  33664              // u32[160] = 640       matmuls done with step s
#define WS_ZEND  34304              // zero [0, WS_ZEND) each launch
#define WS_HDEC  34304              // float[32*128]
#define WS_HENC  50688              // float[32*128]
#define WS_CENC  67072              // float[32*128]
#define WS_END   83456

__device__ __forceinline__ float rlane(float v, int l){
  return __int_as_float(__builtin_amdgcn_readlane(__float_as_int(v), l));
}
__device__ __forceinline__ float sigm(float x){ return 1.f / (1.f + expf(-x)); }

__device__ __forceinline__ unsigned long long packmax(float v, int idx){
  unsigned u = __float_as_uint(v);
  u = (u & 0x80000000u) ? ~u : (u | 0x80000000u);   // monotone float->uint map
  return ((unsigned long long)u << 32) | (unsigned long long)(0xFFFFFFFFu - (unsigned)idx);
}

__device__ __forceinline__ void wait_eq(const unsigned* p, unsigned v){
  while (__hip_atomic_load(p, __ATOMIC_ACQUIRE, __HIP_MEMORY_SCOPE_AGENT) != v)
    __builtin_amdgcn_s_sleep(8);
}

// gate[row=t] = bias + sum_e wih[e]*x[e] + sum_j whh[j]*h[j]; x/h broadcast via readlane
__device__ __forceinline__ float gate_dot(const float (&wih)[EE_], const float (&whh)[HH_],
                                          float bias, float xe, float h0, float h1){
  float a0 = bias, a1 = 0.f, a2 = 0.f, a3 = 0.f;
#pragma unroll
  for (int e = 0; e < EE_; e += 4){
    a0 = fmaf(wih[e+0], rlane(xe, e+0), a0);
    a1 = fmaf(wih[e+1], rlane(xe, e+1), a1);
    a2 = fmaf(wih[e+2], rlane(xe, e+2), a2);
    a3 = fmaf(wih[e+3], rlane(xe, e+3), a3);
  }
#pragma unroll
  for (int j = 0; j < 64; j += 4){
    a0 = fmaf(whh[j+0], rlane(h0, j+0), a0);
    a1 = fmaf(whh[j+1], rlane(h0, j+1), a1);
    a2 = fmaf(whh[j+2], rlane(h0, j+2), a2);
    a3 = fmaf(whh[j+3], rlane(h0, j+3), a3);
  }
#pragma unroll
  for (int j = 0; j < 64; j += 4){
    a0 = fmaf(whh[64+j+0], rlane(h1, j+0), a0);
    a1 = fmaf(whh[64+j+1], rlane(h1, j+1), a1);
    a2 = fmaf(whh[64+j+2], rlane(h1, j+2), a2);
    a3 = fmaf(whh[64+j+3], rlane(h1, j+3), a3);
  }
  return (a0 + a1) + (a2 + a3);
}

// ===================== encoder: 32 wgs (one per batch), no cross-wg deps =====================
__global__ __launch_bounds__(512, 2)
void enc_kernel(const int* __restrict__ xt, const float* __restrict__ embed,
                const float* __restrict__ Wih, const float* __restrict__ Whh,
                const float* __restrict__ bv,
                float* __restrict__ h_out, float* __restrict__ c_out)
{
  const int b = blockIdx.x, t = threadIdx.x, lane = t & 63;
  __shared__ float sh[HH_];
  __shared__ float sg[4*HH_];
  float wih[EE_], whh[HH_];
#pragma unroll
  for (int e = 0; e < EE_; ++e) wih[e] = Wih[t*EE_ + e];
#pragma unroll
  for (int j = 0; j < HH_; ++j) whh[j] = Whh[t*HH_ + j];
  const float bias = bv[t];
  float c = 0.f, hv = 0.f;
  if (t < HH_) sh[t] = 0.f;
  __syncthreads();
#pragma unroll 1
  for (int s = 0; s < TT_; ++s){
    const int tok = xt[b*TT_ + s];
    const float xe = embed[tok*EE_ + lane];
    const float h0 = sh[lane], h1 = sh[64 + lane];
    const float g = gate_dot(wih, whh, bias, xe, h0, h1);
    __syncthreads();   // sh reads done before writes below
    sg[t] = g;
    __syncthreads();
    if (t < HH_){
      const float gi = sg[t], gf = sg[128+t], gg = sg[256+t], go = sg[384+t];
      c = sigm(gf)*c + sigm(gi)*tanhf(gg);
      hv = sigm(go)*tanhf(c);
      sh[t] = hv;
    }
    __syncthreads();
  }
  if (t < HH_){ h_out[b*HH_ + t] = hv; c_out[b*HH_ + t] = c; }
}

// ===================== decoder: persistent, 32 cell wgs + 200 matmul wgs =====================
__global__ __launch_bounds__(512, 2)
void dec_kernel(const float* __restrict__ embed,
                const float* __restrict__ dWih, const float* __restrict__ dWhh,
                const float* __restrict__ db,
                const float* __restrict__ fcw, const float* __restrict__ fcb,
                const float* __restrict__ h_enc, const float* __restrict__ c_enc,
                float* __restrict__ h_dec, unsigned long long* __restrict__ gbest,
                unsigned* __restrict__ hcnt, unsigned* __restrict__ mcnt,
                float* __restrict__ out)
{
  extern __shared__ char smem[];
  const int t = threadIdx.x;
  const int wg = blockIdx.x;

  if (wg < NCELL){
    // ---------------- cell workgroup: owns batch b ----------------
    float* sg = (float*)(smem + OFF_SG);
    float* sh = (float*)(smem + OFF_SH);
    int* stok = (int*)(smem + OFF_TOK);
    const int b = wg, lane = t & 63;
    float wih[EE_], whh[HH_];
#pragma unroll
    for (int e = 0; e < EE_; ++e) wih[e] = dWih[t*EE_ + e];
#pragma unroll
    for (int j = 0; j < HH_; ++j) whh[j] = dWhh[t*HH_ + j];
    const float bias = db[t];
    float c = 0.f;
    if (t < HH_){ c = c_enc[b*HH_ + t]; sh[t] = h_enc[b*HH_ + t]; }
    int tok = 1; // SOS
    __syncthreads();
#pragma unroll 1
    for (int s = 1; s <= TT_; ++s){
      const float xe = embed[tok*EE_ + lane];
      const float h0 = sh[lane], h1 = sh[64 + lane];
      const float g = gate_dot(wih, whh, bias, xe, h0, h1);
      sg[t] = g;
      __syncthreads();
      if (t < HH_){
        const float gi = sg[t], gf = sg[128+t], gg = sg[256+t], go = sg[384+t];
        c = sigm(gf)*c + sigm(gi)*tanhf(gg);
        const float hv = sigm(go)*tanhf(c);
        sh[t] = hv;
        __hip_atomic_store(&h_dec[b*HH_ + t], hv, __ATOMIC_RELAXED, __HIP_MEMORY_SCOPE_AGENT);
      }
      __threadfence();          // drain h stores to coherence point
      __syncthreads();
      if (t == 0){
        __hip_atomic_fetch_add(&hcnt[s], 1u, __ATOMIC_RELEASE, __HIP_MEMORY_SCOPE_AGENT);
        wait_eq(&mcnt[s], (unsigned)NMM);
        const unsigned long long gbv =
            __hip_atomic_load(&gbest[(size_t)s*BB_ + b], __ATOMIC_RELAXED, __HIP_MEMORY_SCOPE_AGENT);
        *stok = (int)(0xFFFFFFFFu - (unsigned)(gbv & 0xFFFFFFFFull));
      }
      __syncthreads();
      tok = *stok;
    }
  } else {
    // ---------------- matmul workgroup: vocab rows [v0, v0+VW) ----------------
    const int widx = wg - NCELL;
    const int v0 = widx * VW;
    float* lhb = (float*)(smem + OFF_LHB);
    float* rdf = (float*)(smem + OFF_RDF);
    const int ks = t >> 7;          // k-split quarter: k in [ks*32, ks*32+32)
    const int u  = t & 127;
    const int vg = u & 31;          // vocab lane; row v = v0 + vi*32 + vg
    const int bg = u >> 5;          // batch group (8 batches each)
    // fc_w fragment lives in REGISTERS for all 128 steps (40 float4 = 160 VGPR)
    float4 wreg[8][5];
#pragma unroll
    for (int vi = 0; vi < 5; ++vi){
      const float4* fw4 = (const float4*)(fcw + (size_t)(v0 + vi*32 + vg)*HH_ + ks*32);
#pragma unroll
      for (int kc = 0; kc < 8; ++kc) wreg[kc][vi] = fw4[kc];
    }
    float fb[5];
#pragma unroll
    for (int vi = 0; vi < 5; ++vi) fb[vi] = fcb[v0 + vi*32 + vg];
    const unsigned long long* hd64 = (const unsigned long long*)h_dec;
    __syncthreads();
#pragma unroll 1
    for (int s = 1; s <= TT_; ++s){
      if (t == 0) wait_eq(&hcnt[s], (unsigned)NCELL);
      __syncthreads();
      // stage h into LDS [b][k] (device-scope loads bypass stale caches)
#pragma unroll
      for (int i = t; i < BB_*HH_/2; i += 512){
        const unsigned long long v =
            __hip_atomic_load(hd64 + i, __ATOMIC_RELAXED, __HIP_MEMORY_SCOPE_AGENT);
        const int bb = i >> 6, k2 = (i & 63)*2;
        float2 f;
        f.x = __uint_as_float((unsigned)(v & 0xFFFFFFFFull));
        f.y = __uint_as_float((unsigned)(v >> 32));
        *(float2*)&lhb[bb*LHB_STRIDE + k2] = f;
      }
      __syncthreads();
      float acc[5][8];
#pragma unroll
      for (int vi = 0; vi < 5; ++vi)
#pragma unroll
        for (int bi = 0; bi < 8; ++bi) acc[vi][bi] = 0.f;
#pragma unroll
      for (int kc = 0; kc < 8; ++kc){
        const int kk = ks*32 + kc*4;
#pragma unroll
        for (int bi = 0; bi < 8; ++bi){
          const float4 hb = *(const float4*)&lhb[(bg*8 + bi)*LHB_STRIDE + kk];  // broadcast read
#pragma unroll
          for (int vi = 0; vi < 5; ++vi){
            const float4 w = wreg[kc][vi];
            acc[vi][bi] = fmaf(w.x,hb.x,fmaf(w.y,hb.y,fmaf(w.z,hb.z,fmaf(w.w,hb.w,acc[vi][bi]))));
          }
        }
      }
      // k-split reduce: ks=1..3 publish, ks=0 combines (stride-41 dwords: <=2-way banks)
      if (ks){
        float* dst = rdf + ((size_t)(ks-1)*128 + u)*41;
#pragma unroll
        for (int vi = 0; vi < 5; ++vi)
#pragma unroll
          for (int bi = 0; bi < 8; ++bi) dst[vi*8 + bi] = acc[vi][bi];
      }
      __syncthreads();
      if (ks == 0){
#pragma unroll
        for (int r = 0; r < 3; ++r){
          const float* src = rdf + ((size_t)r*128 + u)*41;
#pragma unroll
          for (int vi = 0; vi < 5; ++vi)
#pragma unroll
            for (int bi = 0; bi < 8; ++bi) acc[vi][bi] += src[vi*8 + bi];
        }
#pragma unroll
        for (int vi = 0; vi < 5; ++vi)
#pragma unroll
          for (int bi = 0; bi < 8; ++bi) acc[vi][bi] += fb[vi];
        // per-batch argmax over this wg's 160 rows: 5 local + butterfly over 32 vocab lanes
#pragma unroll
        for (int bi = 0; bi < 8; ++bi){
          unsigned long long best = 0ull;
#pragma unroll
          for (int vi = 0; vi < 5; ++vi){
            const unsigned long long pk = packmax(acc[vi][bi], v0 + vi*32 + vg);
            if (pk > best) best = pk;
          }
#pragma unroll
          for (int off = 16; off > 0; off >>= 1){
            const unsigned long long o = __shfl_xor(best, off);
            if (o > best) best = o;
          }
          if (vg == 0)
            __hip_atomic_fetch_max(&gbest[(size_t)s*BB_ + bg*8 + bi], best,
                                   __ATOMIC_RELAXED, __HIP_MEMORY_SCOPE_AGENT);
        }
      }
      __threadfence();            // atomicMax results visible before the count bump
      __syncthreads();
      if (t == 0)
        __hip_atomic_fetch_add(&mcnt[s], 1u, __ATOMIC_RELEASE, __HIP_MEMORY_SCOPE_AGENT);
      // logits written AFTER the handshake: stores drain under the next step
      if (ks == 0){
#pragma unroll
        for (int bi = 0; bi < 8; ++bi){
          float* orow = out + ((size_t)(bg*8 + bi)*TT_ + (s-1))*(size_t)VV_ + v0;
#pragma unroll
          for (int vi = 0; vi < 5; ++vi) orow[vi*32 + vg] = acc[vi][bi];
        }
      }
    }
  }
}

extern "C" void kernel_launch(void* const* d_in, const int* in_sizes, int n_in,
                              void* d_out, int out_size, void* d_ws, size_t ws_size,
                              hipStream_t stream){
  (void)in_sizes; (void)n_in; (void)out_size; (void)ws_size;
  const int*   x     = (const int*)  d_in[0];
  const float* embed = (const float*)d_in[1];
  const float* eWih  = (const float*)d_in[2];
  const float* eWhh  = (const float*)d_in[3];
  const float* eb    = (const float*)d_in[4];
  const float* dWih  = (const float*)d_in[5];
  const float* dWhh  = (const float*)d_in[6];
  const float* db    = (const float*)d_in[7];
  const float* fcw   = (const float*)d_in[8];
  const float* fcb   = (const float*)d_in[9];
  float* out = (float*)d_out;
  char* ws = (char*)d_ws;
  unsigned long long* gbest = (unsigned long long*)(ws + WS_GBEST);
  unsigned* hcnt = (unsigned*)(ws + WS_HCNT);
  unsigned* mcnt = (unsigned*)(ws + WS_MCNT);
  float* h_dec = (float*)(ws + WS_HDEC);
  float* h_enc = (float*)(ws + WS_HENC);
  float* c_enc = (float*)(ws + WS_CENC);

  // zero handshake state every launch (graph node -> deterministic replays)
  hipMemsetAsync(ws, 0, WS_ZEND, stream);
  // allow >64KB dynamic LDS (gfx950 has 160KB/CU); idempotent host-side call
  hipFuncSetAttribute((const void*)dec_kernel, hipFuncAttributeMaxDynamicSharedMemorySize, DYN_LDS);

  enc_kernel<<<NCELL, 512, 0, stream>>>(x, embed, eWih, eWhh, eb, h_enc, c_enc);
  dec_kernel<<<NWG, 512, DYN_LDS, stream>>>(embed, dWih, dWhh, db, fcw, fcb,
                                            h_enc, c_enc, h_dec, gbest, hcnt, mcnt, out);
}